// Round 1
// baseline (352.910 us; speedup 1.0000x reference)
//
#include <hip/hip_runtime.h>
#include <math.h>

#define RANGE 15
#define GRANU 8
#define LTAB 120            // RANGE * GRANU
#define TQ (2 * LTAB + 1)   // 241

// ws layout:
//   float  wsf[0]        = sc
//   float  wsf[1..241]   = table_q value (241 entries)
//   double wsd[0..1]     = sum, sumsq  (at byte offset 1024)

// ---------------------------------------------------------------------------
// Kernel 1: build table_q value + zero reduction scratch.
// table_q[0..120] = 0 ; table_q[121+j] = cumsum(softmax(table/tau))[j] / 15
// ---------------------------------------------------------------------------
__global__ __launch_bounds__(256) void prep_kernel(const float* __restrict__ table,
                                                   const float* __restrict__ tau,
                                                   float* __restrict__ wsf,
                                                   double* __restrict__ wsd) {
    __shared__ float prob[LTAB];
    const int t = threadIdx.x;
    if (t < 2) wsd[t] = 0.0;
    const float tauv = tau[0];
    if (t < RANGE) {
        float y[GRANU];
        float m = -INFINITY;
        #pragma unroll
        for (int c = 0; c < GRANU; ++c) {
            y[c] = table[t * GRANU + c] / tauv;
            m = fmaxf(m, y[c]);
        }
        float e[GRANU];
        float s = 0.0f;
        #pragma unroll
        for (int c = 0; c < GRANU; ++c) {
            e[c] = expf(y[c] - m);
            s += e[c];
        }
        #pragma unroll
        for (int c = 0; c < GRANU; ++c) prob[t * GRANU + c] = e[c] / s;
    }
    __syncthreads();
    if (t == 0) {
        // zeros for indices [0, 120]
        for (int j = 0; j <= LTAB; ++j) wsf[1 + j] = 0.0f;
        // sequential f32 cumsum, divided by RANGE
        float acc = 0.0f;
        for (int j = 0; j < LTAB; ++j) {
            acc += prob[j];
            wsf[1 + (LTAB + 1) + j] = acc / 15.0f;
        }
    }
}

// ---------------------------------------------------------------------------
// Kernel 2: std(x) reduction — ONLY runs its body when scale[0]==0 (lazy-init
// branch of the reference). For the given inputs scale!=0, so every block
// early-exits; cost is just launch overhead.
// ---------------------------------------------------------------------------
__global__ __launch_bounds__(256) void std_reduce_kernel(const float* __restrict__ x,
                                                         const float* __restrict__ scale,
                                                         double* __restrict__ wsd,
                                                         int n) {
    if (scale[0] != 0.0f) return;
    double s = 0.0, s2 = 0.0;
    const int stride = gridDim.x * blockDim.x;
    for (int i = blockIdx.x * blockDim.x + threadIdx.x; i < n; i += stride) {
        double v = (double)x[i];
        s += v;
        s2 += v * v;
    }
    // wave-64 butterfly reduce
    #pragma unroll
    for (int off = 32; off > 0; off >>= 1) {
        s  += __shfl_down(s, off);
        s2 += __shfl_down(s2, off);
    }
    if ((threadIdx.x & 63) == 0) {
        atomicAdd(&wsd[0], s);
        atomicAdd(&wsd[1], s2);
    }
}

// ---------------------------------------------------------------------------
// Kernel 3: finalize sc = exp(scale) or exp(log(3*std)) on the lazy path.
// ---------------------------------------------------------------------------
__global__ void finalize_sc_kernel(const float* __restrict__ scale,
                                   const double* __restrict__ wsd,
                                   float* __restrict__ wsf,
                                   int n) {
    if (threadIdx.x == 0 && blockIdx.x == 0) {
        const float sp = scale[0];
        float sc;
        if (sp != 0.0f) {
            sc = expf(sp);
        } else {
            double sum = wsd[0], sumsq = wsd[1];
            double mean = sum / (double)n;
            double var = (sumsq - sum * mean) / (double)(n - 1);
            float stdf = (float)sqrt(var);
            sc = expf(logf(stdf * 3.0f));  // mimic exp(log(std*3)) ordering
        }
        wsf[0] = sc;
    }
}

// ---------------------------------------------------------------------------
// Kernel 4: main streaming pass.
// out = table_q[ clip(round(clip(x/sc,-1,1)*120)+120, 0, 240) ] * sc
// (literal (tq + g) - g kept for bitwise fidelity to the reference's
//  straight-through expression; it is value-identical to tq.)
// ---------------------------------------------------------------------------
__device__ __forceinline__ float lcq_one(float xv, float sc, const float* __restrict__ tq) {
    float g = xv / sc;                       // IEEE f32 division (matches XLA)
    g = fminf(fmaxf(g, -1.0f), 1.0f);
    int idx = (int)rintf(g * 120.0f) + 120;  // rintf == round-half-even == jnp.round
    idx = min(max(idx, 0), 240);
    return ((tq[idx] + g) - g) * sc;
}

__global__ __launch_bounds__(256) void lookup_kernel(const float4* __restrict__ x4,
                                                     float4* __restrict__ out4,
                                                     const float* __restrict__ x,
                                                     float* __restrict__ out,
                                                     const float* __restrict__ wsf,
                                                     int n4, int n) {
    __shared__ float tq[TQ];
    __shared__ float s_sc;
    for (int i = threadIdx.x; i < TQ; i += 256) tq[i] = wsf[1 + i];
    if (threadIdx.x == 0) s_sc = wsf[0];
    __syncthreads();
    const float sc = s_sc;

    const int gid = blockIdx.x * 256 + threadIdx.x;
    const int stride = gridDim.x * 256;
    for (int i = gid; i < n4; i += stride) {
        float4 v = x4[i];
        float4 o;
        o.x = lcq_one(v.x, sc, tq);
        o.y = lcq_one(v.y, sc, tq);
        o.z = lcq_one(v.z, sc, tq);
        o.w = lcq_one(v.w, sc, tq);
        out4[i] = o;
    }
    // scalar tail (n is divisible by 4 for this problem, but stay general)
    for (int i = n4 * 4 + gid; i < n; i += stride) {
        out[i] = lcq_one(x[i], sc, tq);
    }
}

extern "C" void kernel_launch(void* const* d_in, const int* in_sizes, int n_in,
                              void* d_out, int out_size, void* d_ws, size_t ws_size,
                              hipStream_t stream) {
    const float* x     = (const float*)d_in[0];
    const float* table = (const float*)d_in[1];
    const float* scale = (const float*)d_in[2];
    const float* tau   = (const float*)d_in[3];
    float* out = (float*)d_out;

    float*  wsf = (float*)d_ws;
    double* wsd = (double*)((char*)d_ws + 1024);

    const int n  = in_sizes[0];
    const int n4 = n / 4;

    hipLaunchKernelGGL(prep_kernel, dim3(1), dim3(256), 0, stream, table, tau, wsf, wsd);
    hipLaunchKernelGGL(std_reduce_kernel, dim3(512), dim3(256), 0, stream, x, scale, wsd, n);
    hipLaunchKernelGGL(finalize_sc_kernel, dim3(1), dim3(64), 0, stream, scale, wsd, wsf, n);
    hipLaunchKernelGGL(lookup_kernel, dim3(2048), dim3(256), 0, stream,
                       (const float4*)x, (float4*)out, x, out, wsf, n4, n);
}

// Round 9
// 345.310 us; speedup vs baseline: 1.0220x; 1.0220x over previous
//
#include <hip/hip_runtime.h>
#include <math.h>

#define RANGE 15
#define GRANU 8
#define LTAB 120            // RANGE * GRANU
#define TQ (2 * LTAB + 1)   // 241
#define NPART 512           // std partial-sum blocks (lazy-init path only)

// clang-native 128-bit vector (HIP float4 is a struct; the nontemporal
// builtins require a true vector/scalar type)
typedef float floatx4 __attribute__((ext_vector_type(4)));

// ws layout:
//   float  wsf[0..240]            = table_q value (241 entries)
//   double wsd[0..2*NPART-1]      = per-block (sum, sumsq) partials, at byte 4096

// ---------------------------------------------------------------------------
// Kernel 1 (fused): block 0 builds table_q; blocks 1..NPART compute std
// partial sums (write zeros and exit immediately when scale!=0 — the hot path).
// table_q[0..120]=0 ; table_q[121+j]=cumsum(softmax(table/tau))[j]/15
// ---------------------------------------------------------------------------
__global__ __launch_bounds__(256) void prep_std_kernel(const float* __restrict__ table,
                                                       const float* __restrict__ tau,
                                                       const float* __restrict__ x,
                                                       const float* __restrict__ scale,
                                                       float* __restrict__ wsf,
                                                       double* __restrict__ wsd,
                                                       int n) {
    const int t = threadIdx.x;
    if (blockIdx.x == 0) {
        // ---- table build ----
        __shared__ float prob[LTAB];
        const float tauv = tau[0];
        if (t < RANGE) {
            float y[GRANU];
            float m = -INFINITY;
            #pragma unroll
            for (int c = 0; c < GRANU; ++c) {
                y[c] = table[t * GRANU + c] / tauv;
                m = fmaxf(m, y[c]);
            }
            float e[GRANU];
            float s = 0.0f;
            #pragma unroll
            for (int c = 0; c < GRANU; ++c) {
                e[c] = expf(y[c] - m);
                s += e[c];
            }
            #pragma unroll
            for (int c = 0; c < GRANU; ++c) prob[t * GRANU + c] = e[c] / s;
        }
        __syncthreads();
        if (t == 0) {
            for (int j = 0; j <= LTAB; ++j) wsf[j] = 0.0f;     // indices [0,120]
            float acc = 0.0f;                                   // sequential f32 cumsum
            for (int j = 0; j < LTAB; ++j) {
                acc += prob[j];
                wsf[(LTAB + 1) + j] = acc / 15.0f;
            }
        }
        return;
    }
    // ---- std partials (blocks 1..NPART) ----
    const int b = blockIdx.x - 1;
    if (scale[0] != 0.0f) {               // hot path: reference skips std entirely
        if (t == 0) { wsd[2 * b] = 0.0; wsd[2 * b + 1] = 0.0; }
        return;
    }
    double s = 0.0, s2 = 0.0;
    const int stride = NPART * 256;
    for (int i = b * 256 + t; i < n; i += stride) {
        double v = (double)x[i];
        s += v;
        s2 += v * v;
    }
    __shared__ double red[2][4];
    #pragma unroll
    for (int off = 32; off > 0; off >>= 1) {
        s  += __shfl_down(s, off);
        s2 += __shfl_down(s2, off);
    }
    if ((t & 63) == 0) { red[0][t >> 6] = s; red[1][t >> 6] = s2; }
    __syncthreads();
    if (t == 0) {
        wsd[2 * b]     = red[0][0] + red[0][1] + red[0][2] + red[0][3];
        wsd[2 * b + 1] = red[1][0] + red[1][1] + red[1][2] + red[1][3];
    }
}

// ---------------------------------------------------------------------------
// Kernel 2: streaming lookup. sc computed per-block (wave-uniform, ~free on
// the hot path; lazy path reduces the NPART partials serially in thread 0).
// out = table_q[ clip(round(clip(x/sc,-1,1)*120)+120, 0, 240) ] * sc
// (literal (tq+g)-g kept for fidelity to the straight-through expression.)
// ---------------------------------------------------------------------------
__device__ __forceinline__ float lcq_one(float xv, float sc, const float* __restrict__ tq) {
    float g = xv / sc;                       // IEEE f32 div (matches XLA)
    g = fminf(fmaxf(g, -1.0f), 1.0f);
    int idx = (int)rintf(g * 120.0f) + 120;  // rintf == round-half-even == jnp.round
    idx = min(max(idx, 0), 240);
    return ((tq[idx] + g) - g) * sc;
}

__global__ __launch_bounds__(256) void lookup_kernel(const floatx4* __restrict__ x4,
                                                     floatx4* __restrict__ out4,
                                                     const float* __restrict__ x,
                                                     float* __restrict__ out,
                                                     const float* __restrict__ scale,
                                                     const float* __restrict__ wsf,
                                                     const double* __restrict__ wsd,
                                                     int n4, int n) {
    __shared__ float tq[TQ];
    __shared__ float s_sc;
    for (int i = threadIdx.x; i < TQ; i += 256) tq[i] = wsf[i];
    if (threadIdx.x == 0) {
        const float sp = scale[0];
        float sc;
        if (sp != 0.0f) {
            sc = expf(sp);
        } else {
            double sum = 0.0, sumsq = 0.0;
            for (int b = 0; b < NPART; ++b) { sum += wsd[2 * b]; sumsq += wsd[2 * b + 1]; }
            double mean = sum / (double)n;
            double var = (sumsq - sum * mean) / (double)(n - 1);
            sc = expf(logf((float)sqrt(var) * 3.0f));  // exp(log(std*3)) ordering
        }
        s_sc = sc;
    }
    __syncthreads();
    const float sc = s_sc;

    int i = blockIdx.x * 256 + threadIdx.x;
    const int stride = gridDim.x * 256;
    // unroll x2: both (non-temporal) loads in flight before either compute chain
    for (; i + stride < n4; i += 2 * stride) {
        floatx4 a = __builtin_nontemporal_load(&x4[i]);
        floatx4 b = __builtin_nontemporal_load(&x4[i + stride]);
        floatx4 oa, ob;
        oa.x = lcq_one(a.x, sc, tq); oa.y = lcq_one(a.y, sc, tq);
        oa.z = lcq_one(a.z, sc, tq); oa.w = lcq_one(a.w, sc, tq);
        ob.x = lcq_one(b.x, sc, tq); ob.y = lcq_one(b.y, sc, tq);
        ob.z = lcq_one(b.z, sc, tq); ob.w = lcq_one(b.w, sc, tq);
        __builtin_nontemporal_store(oa, &out4[i]);
        __builtin_nontemporal_store(ob, &out4[i + stride]);
    }
    for (; i < n4; i += stride) {
        floatx4 a = __builtin_nontemporal_load(&x4[i]);
        floatx4 oa;
        oa.x = lcq_one(a.x, sc, tq); oa.y = lcq_one(a.y, sc, tq);
        oa.z = lcq_one(a.z, sc, tq); oa.w = lcq_one(a.w, sc, tq);
        __builtin_nontemporal_store(oa, &out4[i]);
    }
    // scalar tail (empty for this shape; kept general)
    for (int j = n4 * 4 + blockIdx.x * 256 + threadIdx.x; j < n; j += stride) {
        out[j] = lcq_one(x[j], sc, tq);
    }
}

extern "C" void kernel_launch(void* const* d_in, const int* in_sizes, int n_in,
                              void* d_out, int out_size, void* d_ws, size_t ws_size,
                              hipStream_t stream) {
    const float* x     = (const float*)d_in[0];
    const float* table = (const float*)d_in[1];
    const float* scale = (const float*)d_in[2];
    const float* tau   = (const float*)d_in[3];
    float* out = (float*)d_out;

    float*  wsf = (float*)d_ws;
    double* wsd = (double*)((char*)d_ws + 4096);

    const int n  = in_sizes[0];
    const int n4 = n / 4;

    hipLaunchKernelGGL(prep_std_kernel, dim3(NPART + 1), dim3(256), 0, stream,
                       table, tau, x, scale, wsf, wsd, n);
    hipLaunchKernelGGL(lookup_kernel, dim3(2048), dim3(256), 0, stream,
                       (const floatx4*)x, (floatx4*)out, x, out, scale, wsf, wsd, n4, n);
}